// Round 4
// baseline (2692.459 us; speedup 1.0000x reference)
//
#include <hip/hip_runtime.h>
#include <hip/hip_fp16.h>
#include <cstdint>

#define NS 25
#define CD 128
#define HD 512
#define GTOT 6144  // per-node gate cols: 2*2560 (eq, l-major) + 2*512 (ne)

typedef _Float16 f16;
typedef f16 f16x8 __attribute__((ext_vector_type(8)));
typedef f16 f16x4 __attribute__((ext_vector_type(4)));
typedef float f32x4 __attribute__((ext_vector_type(4)));

__device__ __forceinline__ float silu_f(float x) { return x / (1.f + __expf(-x)); }

// ---------- edge segment-sum via atomics ----------
__global__ void edge_kernel(const float* __restrict__ t_ij, const int* __restrict__ dst_idx,
                            float* __restrict__ csum, float* __restrict__ cnt, int E) {
    int tid = blockIdx.x * blockDim.x + threadIdx.x;
    int e = tid >> 5, g = tid & 31;
    if (e >= E) return;
    float4 tv = *(const float4*)(t_ij + (size_t)e * CD + g * 4);
    int d = dst_idx[e];
    float* p = csum + (size_t)d * CD + g * 4;
    atomicAdd(p + 0, tv.x); atomicAdd(p + 1, tv.y);
    atomicAdd(p + 2, tv.z); atomicAdd(p + 3, tv.w);
    if (g == 0) atomicAdd(cnt + d, 1.f);
}

// ---------- per-node: c_i (in place) + router softmax ----------
__global__ void gating_kernel(float* __restrict__ csum, const float* __restrict__ cnt,
                              const float* __restrict__ rW1, const float* __restrict__ rb1,
                              const float* __restrict__ rW2, const float* __restrict__ rb2,
                              float* __restrict__ wout, int N) {
    __shared__ float ci[CD], r1[CD], r2[4];
    int n = blockIdx.x, t = threadIdx.x;
    float cn = fmaxf(cnt[n], 1.f);
    float v = csum[(size_t)n * CD + t] / cn;
    ci[t] = v;
    csum[(size_t)n * CD + t] = v;
    __syncthreads();
    float acc = rb1[t];
    for (int c = 0; c < CD; ++c) acc += ci[c] * rW1[c * CD + t];
    r1[t] = silu_f(acc);
    __syncthreads();
    if (t < 4) {
        float a = rb2[t];
        for (int c = 0; c < CD; ++c) a += r1[c] * rW2[c * 4 + t];
        r2[t] = a;
    }
    __syncthreads();
    if (t == 0) {
        float m = fmaxf(fmaxf(r2[0], r2[1]), fmaxf(r2[2], r2[3]));
        float e0 = __expf(r2[0] - m), e1 = __expf(r2[1] - m);
        float e2 = __expf(r2[2] - m), e3 = __expf(r2[3] - m);
        float s = e0 + e1 + e2 + e3;
        wout[(size_t)n * 4 + 0] = e0 / s;
        wout[(size_t)n * 4 + 1] = e1 / s;
        wout[(size_t)n * 4 + 2] = e2 / s;
        wout[(size_t)n * 4 + 3] = e3 / s;
    }
}

// ---------- batched gate GEMM: gout[n, goff+col] = f16(silu(c_i·gW[:,col]+gb[col])) ----------
__global__ __launch_bounds__(256) void gate_kernel(
        const float* __restrict__ c_i, const float* __restrict__ gW,
        const float* __restrict__ gb, __half* __restrict__ gout,
        int N, int L, int goff) {
    __shared__ float cis[32][CD];
    int nb = blockIdx.x * 32;
    int col = blockIdx.y * 256 + threadIdx.x;
    for (int i = threadIdx.x; i < 32 * CD; i += 256) {
        int nn = i >> 7, c = i & 127;
        int n = nb + nn;
        cis[nn][c] = (n < N) ? c_i[(size_t)n * CD + c] : 0.f;
    }
    __syncthreads();
    float b = gb[col];
    float acc[32];
#pragma unroll
    for (int i = 0; i < 32; ++i) acc[i] = b;
    for (int c = 0; c < CD; ++c) {
        float g = gW[(size_t)c * L + col];
#pragma unroll
        for (int i = 0; i < 32; ++i) acc[i] += cis[i][c] * g;
    }
    for (int i = 0; i < 32; ++i) {
        int n = nb + i;
        if (n < N) gout[(size_t)n * GTOT + goff + col] = __float2half(silu_f(acc[i]));
    }
}

// ---------- weight transpose+cvt: W1Th[e][hcol 512][c 128] = f16(W1[e][c][hcol]) ----------
__global__ void cvtw1_k(const float* __restrict__ eqw, const float* __restrict__ new_,
                        f16* __restrict__ dst) {
    int idx = blockIdx.x * blockDim.x + threadIdx.x;
    if (idx >= 4 * HD * CD) return;
    int e = idx >> 16, rem = idx & 65535;
    int hcol = rem >> 7, c = rem & 127;
    const float* src = (e < 2) ? (eqw + (size_t)e * CD * HD) : (new_ + (size_t)(e - 2) * CD * HD);
    dst[idx] = (f16)src[(size_t)c * HD + hcol];
}
// ---------- W2Th[e][c2 128][k 512] = f16(W2[e][k][c2]) ----------
__global__ void cvtw2_k(const float* __restrict__ eqw, const float* __restrict__ new_,
                        f16* __restrict__ dst) {
    int idx = blockIdx.x * blockDim.x + threadIdx.x;
    if (idx >= 4 * HD * CD) return;
    int e = idx >> 16, rem = idx & 65535;
    int c2 = rem >> 9, k = rem & 511;
    const float* src = (e < 2) ? (eqw + (size_t)e * HD * CD) : (new_ + (size_t)(e - 2) * HD * CD);
    dst[idx] = (f16)src[(size_t)k * CD + c2];
}

// ---------- fused MFMA expert kernel: 125 rows (5 nodes) per block, 4 waves ----------
// Swapped-operand MFMA both stages: stage1 D=h^T (A=W1T,B=x), stage2 D=out^T (A=W2T,B=h).
// A/B frag: 16-dim = lane&15, k = (lane>>4)*8+elem (contiguous b128).
// C/D: col(=16-dim of B) = lane&15, row(=16-dim of A) = (lane>>4)*4+reg  [m89].
__global__ __launch_bounds__(256) void moe_kernel(
    const float* __restrict__ x_emb, const float* __restrict__ wsm,
    const f16* __restrict__ gts,
    const f16* __restrict__ W1Th, const f16* __restrict__ W2Th,
    const float* __restrict__ ne_b1, const float* __restrict__ ne_b2,
    float* __restrict__ out, int N, int Mtot)
{
    __shared__ f16 xS[128 * 128];   // 32 KB, swizzled rows of 256B
    __shared__ f16 hS[128 * 64];    // 16 KB, swizzled rows of 128B (one 64-hcol colpass)
    __shared__ f16 gS[25 * 512];    // 25 KB, swizzled rows of 1024B

    const int t = threadIdx.x;
    const int lane = t & 63;
    const int lr = lane & 15, lq = lane >> 4;
    const int wid = t >> 6, wr = wid >> 1, wc = wid & 1;
    const int rowbase = blockIdx.x * 125;
    const int n0 = blockIdx.x * 5;

    // ---- stage x tile into LDS (f32 -> f16, swizzled) ----
    for (int u = t; u < 128 * 32; u += 256) {
        int r = u >> 5, c4 = u & 31;
        int rg = rowbase + (r < 125 ? r : 124);
        if (rg > Mtot - 1) rg = Mtot - 1;
        float4 v = *(const float4*)(x_emb + (size_t)rg * CD + c4 * 4);
        f16x4 hv; hv[0] = (f16)v.x; hv[1] = (f16)v.y; hv[2] = (f16)v.z; hv[3] = (f16)v.w;
        int byte = (r * 256 + c4 * 8) ^ ((r & 7) << 4);
        *(f16x4*)((char*)xS + byte) = hv;
    }

    // ---- per-j row metadata (rows = wr*64 + j*16 + lr) ----
    int n_j[4], nl_eq[4], nl_ne[4], srow_j[4];
    bool s0_j[4], valid_j[4];
#pragma unroll
    for (int j = 0; j < 4; ++j) {
        int rl = wr * 64 + j * 16 + lr;
        int rlc = rl < 125 ? rl : 124;
        int rc = rowbase + rlc;
        if (rc > Mtot - 1) rc = Mtot - 1;
        int n = rc / 25;
        int s = rc - n * 25;
        int l = (int)sqrtf((float)s);          // floor(sqrt(s)) = degree l
        n_j[j] = n;
        s0_j[j] = (s == 0);
        nl_eq[j] = (n - n0) * 5 + l;
        nl_ne[j] = n - n0;
        srow_j[j] = rowbase + rl;
        valid_j[j] = (rl < 125) && (rowbase + rl < Mtot);
    }

    f32x4 acco[4][4];
#pragma unroll
    for (int i = 0; i < 4; ++i)
#pragma unroll
        for (int j = 0; j < 4; ++j) acco[i][j] = (f32x4){0.f, 0.f, 0.f, 0.f};

    __syncthreads();   // xS (and e=0 gates, staged below before first use) ready

    for (int e = 0; e < 4; ++e) {
        const bool is_eq = (e < 2);
        const int goff = (e == 0) ? 0 : (e == 1) ? 2560 : (e == 2) ? 5120 : 5632;
        const int grows = is_eq ? 25 : 5;

        // stage gates for this expert (gS readers of prev expert all done: see barrier notes)
        for (int u = t; u < grows * 64; u += 256) {
            int nl = u >> 6, rem = u & 63;
            int node, loff;
            if (is_eq) { int nd = nl / 5; node = n0 + nd; loff = (nl - 5 * nd) * 512; }
            else       { node = n0 + nl; loff = 0; }
            if (node > N - 1) node = N - 1;
            f16x8 g = *(const f16x8*)(gts + (size_t)node * GTOT + goff + loff + rem * 8);
            int byte = (nl * 1024 + rem * 16) ^ ((nl & 7) << 4);
            *(f16x8*)((char*)gS + byte) = g;
        }
        float wk_j[4];
#pragma unroll
        for (int j = 0; j < 4; ++j) wk_j[j] = wsm[(size_t)n_j[j] * 4 + e];

        const f16* w1e = W1Th + ((size_t)e << 16);
        const f16* w2e = W2Th + ((size_t)e << 16);

        for (int p = 0; p < 8; ++p) {
            // ---- stage1: h^T = W1T x^T for 64 hcols (this colpass), K=128 ----
            f32x4 acch[2][4];
#pragma unroll
            for (int i = 0; i < 2; ++i)
#pragma unroll
                for (int j = 0; j < 4; ++j) acch[i][j] = (f32x4){0.f, 0.f, 0.f, 0.f};
#pragma unroll
            for (int ks = 0; ks < 4; ++ks) {
                f16x8 a0, a1, b[4];
                {
                    int hc0 = p * 64 + wc * 32 + 0 * 16 + lr;
                    int hc1 = p * 64 + wc * 32 + 1 * 16 + lr;
                    a0 = *(const f16x8*)(w1e + (size_t)hc0 * CD + ks * 32 + lq * 8);
                    a1 = *(const f16x8*)(w1e + (size_t)hc1 * CD + ks * 32 + lq * 8);
                }
#pragma unroll
                for (int j = 0; j < 4; ++j) {
                    int rl = wr * 64 + j * 16 + lr;
                    int byte = (rl * 256 + (ks * 32 + lq * 8) * 2) ^ ((rl & 7) << 4);
                    b[j] = *(const f16x8*)((char*)xS + byte);
                }
#pragma unroll
                for (int j = 0; j < 4; ++j) {
                    acch[0][j] = __builtin_amdgcn_mfma_f32_16x16x32_f16(a0, b[j], acch[0][j], 0, 0, 0);
                    acch[1][j] = __builtin_amdgcn_mfma_f32_16x16x32_f16(a1, b[j], acch[1][j], 0, 0, 0);
                }
            }
            __syncthreads();   // prev colpass's hS readers done; gS staged (p==0 case)

            // ---- epilogue: act+gate+wk, pack f16, write hS ----
#pragma unroll
            for (int i = 0; i < 2; ++i) {
                const int hcolb = p * 64 + wc * 32 + i * 16 + lq * 4;   // global hcol of reg 0
#pragma unroll
                for (int j = 0; j < 4; ++j) {
                    float v0 = acch[i][j][0], v1 = acch[i][j][1];
                    float v2 = acch[i][j][2], v3 = acch[i][j][3];
                    if (is_eq) {
                        int gbyte = (nl_eq[j] * 1024 + hcolb * 2) ^ ((nl_eq[j] & 7) << 4);
                        f16x4 g = *(const f16x4*)((char*)gS + gbyte);
                        if (s0_j[j]) { v0 = silu_f(v0); v1 = silu_f(v1); v2 = silu_f(v2); v3 = silu_f(v3); }
                        float w = wk_j[j];
                        v0 *= (float)g[0] * w; v1 *= (float)g[1] * w;
                        v2 *= (float)g[2] * w; v3 *= (float)g[3] * w;
                    } else {
                        float4 b1v = *(const float4*)(ne_b1 + (size_t)(e - 2) * HD + hcolb);
                        int gbyte = (nl_ne[j] * 1024 + hcolb * 2) ^ ((nl_ne[j] & 7) << 4);
                        f16x4 g = *(const f16x4*)((char*)gS + gbyte);
                        float w = wk_j[j];
                        v0 = silu_f(v0 + b1v.x) * (float)g[0] * w;
                        v1 = silu_f(v1 + b1v.y) * (float)g[1] * w;
                        v2 = silu_f(v2 + b1v.z) * (float)g[2] * w;
                        v3 = silu_f(v3 + b1v.w) * (float)g[3] * w;
                    }
                    int rl = wr * 64 + j * 16 + lr;
                    int hloc = wc * 32 + i * 16 + lq * 4;
                    int byte = (rl * 128 + hloc * 2) ^ ((rl & 7) << 4);
                    f16x4 hv; hv[0] = (f16)v0; hv[1] = (f16)v1; hv[2] = (f16)v2; hv[3] = (f16)v3;
                    *(f16x4*)((char*)hS + byte) = hv;
                }
            }
            __syncthreads();

            // ---- stage2: out^T += W2T[., pk..] h^T[pk..], K=64 ----
#pragma unroll
            for (int ks = 0; ks < 2; ++ks) {
                f16x8 a2[4], b2[4];
#pragma unroll
                for (int i2 = 0; i2 < 4; ++i2) {
                    int c2 = wc * 64 + i2 * 16 + lr;
                    a2[i2] = *(const f16x8*)(w2e + (size_t)c2 * HD + p * 64 + ks * 32 + lq * 8);
                }
#pragma unroll
                for (int j2 = 0; j2 < 4; ++j2) {
                    int rl = wr * 64 + j2 * 16 + lr;
                    int byte = (rl * 128 + (ks * 32 + lq * 8) * 2) ^ ((rl & 7) << 4);
                    b2[j2] = *(const f16x8*)((char*)hS + byte);
                }
#pragma unroll
                for (int i2 = 0; i2 < 4; ++i2)
#pragma unroll
                    for (int j2 = 0; j2 < 4; ++j2)
                        acco[i2][j2] = __builtin_amdgcn_mfma_f32_16x16x32_f16(a2[i2], b2[j2], acco[i2][j2], 0, 0, 0);
            }
        } // colpass
    } // expert

    // ---- final epilogue: + wk2*b2_ne0 + wk3*b2_ne1, store ----
#pragma unroll
    for (int j2 = 0; j2 < 4; ++j2) {
        if (!valid_j[j2]) continue;
        float wk2 = wsm[(size_t)n_j[j2] * 4 + 2];
        float wk3 = wsm[(size_t)n_j[j2] * 4 + 3];
#pragma unroll
        for (int i2 = 0; i2 < 4; ++i2) {
            int c2b = wc * 64 + i2 * 16 + lq * 4;
            float4 ba = *(const float4*)(ne_b2 + c2b);
            float4 bb = *(const float4*)(ne_b2 + CD + c2b);
            float4 o;
            o.x = acco[i2][j2][0] + wk2 * ba.x + wk3 * bb.x;
            o.y = acco[i2][j2][1] + wk2 * ba.y + wk3 * bb.y;
            o.z = acco[i2][j2][2] + wk2 * ba.z + wk3 * bb.z;
            o.w = acco[i2][j2][3] + wk2 * ba.w + wk3 * bb.w;
            *(float4*)(out + (size_t)srow_j[j2] * CD + c2b) = o;
        }
    }
}

extern "C" void kernel_launch(void* const* d_in, const int* in_sizes, int n_in,
                              void* d_out, int out_size, void* d_ws, size_t ws_size,
                              hipStream_t stream) {
    const float* x_emb = (const float*)d_in[0];
    const float* t_ij  = (const float*)d_in[1];
    const int*   eidx  = (const int*)d_in[2];
    const float* rW1   = (const float*)d_in[3];
    const float* rb1   = (const float*)d_in[4];
    const float* rW2   = (const float*)d_in[5];
    const float* rb2   = (const float*)d_in[6];
    const float* eq_W1 = (const float*)d_in[7];
    const float* eq_gW = (const float*)d_in[8];
    const float* eq_gb = (const float*)d_in[9];
    const float* eq_W2 = (const float*)d_in[10];
    const float* ne_W1 = (const float*)d_in[11];
    const float* ne_b1 = (const float*)d_in[12];
    const float* ne_gW = (const float*)d_in[13];
    const float* ne_gb = (const float*)d_in[14];
    const float* ne_W2 = (const float*)d_in[15];
    const float* ne_b2 = (const float*)d_in[16];
    float* out = (float*)d_out;

    const int N = in_sizes[0] / (NS * CD);
    const int E = in_sizes[1] / CD;
    const int Mtot = N * NS;

    char* ws = (char*)d_ws;
    size_t off = 0;
    auto alloc = [&](size_t bytes) {
        void* p = ws + off;
        off = (off + bytes + 255) & ~(size_t)255;
        return p;
    };
    float*  csum = (float*)alloc((size_t)N * CD * 4);   // becomes c_i in place
    float*  cnt  = (float*)alloc((size_t)N * 4);
    float*  wsm  = (float*)alloc((size_t)N * 4 * 4);
    __half* gts  = (__half*)alloc((size_t)N * GTOT * 2);
    f16*    W1Th = (f16*)alloc((size_t)4 * HD * CD * 2);
    f16*    W2Th = (f16*)alloc((size_t)4 * HD * CD * 2);

    hipMemsetAsync(csum, 0, (size_t)N * CD * 4, stream);
    hipMemsetAsync(cnt,  0, (size_t)N * 4, stream);

    // weight cvt+transpose (f16)
    cvtw1_k<<<(4 * HD * CD + 255) / 256, 256, 0, stream>>>(eq_W1, ne_W1, W1Th);
    cvtw2_k<<<(4 * HD * CD + 255) / 256, 256, 0, stream>>>(eq_W2, ne_W2, W2Th);

    // segment sums
    long tot_e = (long)E * 32;
    edge_kernel<<<(int)((tot_e + 255) / 256), 256, 0, stream>>>(t_ij, eidx + E, csum, cnt, E);

    // c_i + router weights
    gating_kernel<<<N, CD, 0, stream>>>(csum, cnt, rW1, rb1, rW2, rb2, wsm, N);

    // gate GEMMs (f16 output, [n][l-major 512] per eq expert)
    dim3 g1((N + 31) / 32, 2560 / 256);
    gate_kernel<<<g1, 256, 0, stream>>>(csum, eq_gW, eq_gb, gts, N, 2560, 0);
    gate_kernel<<<g1, 256, 0, stream>>>(csum, eq_gW + (size_t)CD * 2560, eq_gb + 2560, gts, N, 2560, 2560);
    dim3 g2((N + 31) / 32, 512 / 256);
    gate_kernel<<<g2, 256, 0, stream>>>(csum, ne_gW, ne_gb, gts, N, 512, 5120);
    gate_kernel<<<g2, 256, 0, stream>>>(csum, ne_gW + (size_t)CD * 512, ne_gb + 512, gts, N, 512, 5632);

    // fused MFMA experts
    moe_kernel<<<(Mtot + 124) / 125, 256, 0, stream>>>(
        x_emb, wsm, (const f16*)gts, W1Th, W2Th, ne_b1, ne_b2, out, N, Mtot);
}

// Round 5
// 2489.291 us; speedup vs baseline: 1.0816x; 1.0816x over previous
//
#include <hip/hip_runtime.h>
#include <cstdint>

#define NS 25
#define CD 128
#define HD 512
#define GTOT 6144  // packed gate cols: eq0 2560 (l-major) | eq1 2560 | ne0 512 | ne1 512

typedef _Float16 f16;
typedef f16 f16x8 __attribute__((ext_vector_type(8)));
typedef f16 f16x4 __attribute__((ext_vector_type(4)));
typedef float f32x4 __attribute__((ext_vector_type(4)));

__device__ __forceinline__ float silu_f(float x) {
    return x * __builtin_amdgcn_rcpf(1.f + __expf(-x));
}

// ---------- edge segment-sum via atomics ----------
__global__ void edge_kernel(const float* __restrict__ t_ij, const int* __restrict__ dst_idx,
                            float* __restrict__ csum, float* __restrict__ cnt, int E) {
    int tid = blockIdx.x * blockDim.x + threadIdx.x;
    int e = tid >> 5, g = tid & 31;
    if (e >= E) return;
    float4 tv = *(const float4*)(t_ij + (size_t)e * CD + g * 4);
    int d = dst_idx[e];
    float* p = csum + (size_t)d * CD + g * 4;
    atomicAdd(p + 0, tv.x); atomicAdd(p + 1, tv.y);
    atomicAdd(p + 2, tv.z); atomicAdd(p + 3, tv.w);
    if (g == 0) atomicAdd(cnt + d, 1.f);
}

// ---------- per-node: c_i (in place) + router softmax ----------
__global__ void gating_kernel(float* __restrict__ csum, const float* __restrict__ cnt,
                              const float* __restrict__ rW1, const float* __restrict__ rb1,
                              const float* __restrict__ rW2, const float* __restrict__ rb2,
                              float* __restrict__ wout, int N) {
    __shared__ float ci[CD], r1[CD], r2[4];
    int n = blockIdx.x, t = threadIdx.x;
    float cn = fmaxf(cnt[n], 1.f);
    float v = csum[(size_t)n * CD + t] / cn;
    ci[t] = v;
    csum[(size_t)n * CD + t] = v;
    __syncthreads();
    float acc = rb1[t];
    for (int c = 0; c < CD; ++c) acc += ci[c] * rW1[c * CD + t];
    r1[t] = silu_f(acc);
    __syncthreads();
    if (t < 4) {
        float a = rb2[t];
        for (int c = 0; c < CD; ++c) a += r1[c] * rW2[c * 4 + t];
        r2[t] = a;
    }
    __syncthreads();
    if (t == 0) {
        float m = fmaxf(fmaxf(r2[0], r2[1]), fmaxf(r2[2], r2[3]));
        float e0 = __expf(r2[0] - m), e1 = __expf(r2[1] - m);
        float e2 = __expf(r2[2] - m), e3 = __expf(r2[3] - m);
        float s = e0 + e1 + e2 + e3;
        wout[(size_t)n * 4 + 0] = e0 / s;
        wout[(size_t)n * 4 + 1] = e1 / s;
        wout[(size_t)n * 4 + 2] = e2 / s;
        wout[(size_t)n * 4 + 3] = e3 / s;
    }
}

// ---------- weight cvt: W1Th[e][hcol 512][c 128] = f16(W1[e][c][hcol]) ----------
__global__ void cvtw1_k(const float* __restrict__ eqw, const float* __restrict__ new_,
                        f16* __restrict__ dst) {
    int idx = blockIdx.x * blockDim.x + threadIdx.x;
    if (idx >= 4 * HD * CD) return;
    int e = idx >> 16, rem = idx & 65535;
    int hcol = rem >> 7, c = rem & 127;
    const float* src = (e < 2) ? (eqw + (size_t)e * CD * HD) : (new_ + (size_t)(e - 2) * CD * HD);
    dst[idx] = (f16)src[(size_t)c * HD + hcol];
}
// ---------- W2Th[e][c2 128][k 512] = f16(W2[e][k][c2]) ----------
__global__ void cvtw2_k(const float* __restrict__ eqw, const float* __restrict__ new_,
                        f16* __restrict__ dst) {
    int idx = blockIdx.x * blockDim.x + threadIdx.x;
    if (idx >= 4 * HD * CD) return;
    int e = idx >> 16, rem = idx & 65535;
    int c2 = rem >> 9, k = rem & 511;
    const float* src = (e < 2) ? (eqw + (size_t)e * HD * CD) : (new_ + (size_t)(e - 2) * HD * CD);
    dst[idx] = (f16)src[(size_t)k * CD + c2];
}

// ---------- packed gate weights: gPW[j 6144][c 128] = f16(gW[c][j]), gPB[j] = gb[j] ----------
__global__ void cvtgw_k(const float* __restrict__ eq_gW, const float* __restrict__ eq_gb,
                        const float* __restrict__ ne_gW, const float* __restrict__ ne_gb,
                        f16* __restrict__ gPW, float* __restrict__ gPB) {
    int idx = blockIdx.x * blockDim.x + threadIdx.x;
    if (idx >= GTOT * CD) return;
    int j = idx >> 7, c = idx & 127;
    float v;
    if (j < 5120) {
        int k = (j < 2560) ? 0 : 1;
        int col = j - k * 2560;
        v = eq_gW[(size_t)k * CD * 2560 + (size_t)c * 2560 + col];
    } else {
        int jj = j - 5120;
        int k = jj >> 9, col = jj & 511;
        v = ne_gW[(size_t)k * CD * 512 + (size_t)c * 512 + col];
    }
    gPW[idx] = (f16)v;
    if (c == 0) gPB[j] = (j < 5120) ? eq_gb[j] : ne_gb[j - 5120];
}

// ---------- MFMA gate GEMM: gts[n][j] = f16(silu(c_i[n]·gPW[j] + gPB[j])) ----------
// Swapped: A = gPW (16-dim = gate col), B = c_i (16-dim = node). D: col=lane&15=node, row=lq*4+reg=gatecol.
__global__ __launch_bounds__(256) void gatemm_k(
        const float* __restrict__ c_i, const f16* __restrict__ gPW,
        const float* __restrict__ gPB, f16* __restrict__ gts, int N) {
    __shared__ f16 cS[32 * 128];     // 8 KB, 256B pitch, swizzled
    __shared__ f16 gtile[32 * 256];  // 16 KB, 512B pitch, swizzled
    const int t = threadIdx.x;
    const int lane = t & 63, lr = lane & 15, lq = lane >> 4, wid = t >> 6;
    const int nb = blockIdx.x * 32, cb = blockIdx.y * 256;

    for (int u = t; u < 32 * 32; u += 256) {
        int r = u >> 5, c4 = u & 31;
        int n = nb + r; if (n > N - 1) n = N - 1;
        float4 v = *(const float4*)(c_i + (size_t)n * CD + c4 * 4);
        f16x4 hv; hv[0] = (f16)v.x; hv[1] = (f16)v.y; hv[2] = (f16)v.z; hv[3] = (f16)v.w;
        int byte = (r * 256 + c4 * 8) ^ ((r & 7) << 4);
        *(f16x4*)((char*)cS + byte) = hv;
    }
    __syncthreads();

    f32x4 acc[4][2];
#pragma unroll
    for (int i = 0; i < 4; ++i) { acc[i][0] = (f32x4){0,0,0,0}; acc[i][1] = (f32x4){0,0,0,0}; }
#pragma unroll
    for (int ks = 0; ks < 4; ++ks) {
        f16x8 b[2], a[4];
#pragma unroll
        for (int j = 0; j < 2; ++j) {
            int rl = j * 16 + lr;
            int byte = (rl * 256 + (ks * 32 + lq * 8) * 2) ^ ((rl & 7) << 4);
            b[j] = *(const f16x8*)((char*)cS + byte);
        }
#pragma unroll
        for (int i = 0; i < 4; ++i)
            a[i] = *(const f16x8*)(gPW + (size_t)(cb + wid * 64 + i * 16 + lr) * CD + ks * 32 + lq * 8);
#pragma unroll
        for (int i = 0; i < 4; ++i)
#pragma unroll
            for (int j = 0; j < 2; ++j)
                acc[i][j] = __builtin_amdgcn_mfma_f32_16x16x32_f16(a[i], b[j], acc[i][j], 0, 0, 0);
    }
#pragma unroll
    for (int i = 0; i < 4; ++i) {
        int clb = wid * 64 + i * 16 + lq * 4;
        float4 bi = *(const float4*)(gPB + cb + clb);
#pragma unroll
        for (int j = 0; j < 2; ++j) {
            f16x4 g;
            g[0] = (f16)silu_f(acc[i][j][0] + bi.x);
            g[1] = (f16)silu_f(acc[i][j][1] + bi.y);
            g[2] = (f16)silu_f(acc[i][j][2] + bi.z);
            g[3] = (f16)silu_f(acc[i][j][3] + bi.w);
            int nl = j * 16 + lr;
            int byte = (nl * 512 + clb * 2) ^ ((nl & 7) << 4);
            *(f16x4*)((char*)gtile + byte) = g;
        }
    }
    __syncthreads();
    for (int u = t; u < 32 * 32; u += 256) {
        int r = u >> 5, c8 = u & 31;
        int byte = (r * 512 + c8 * 16) ^ ((r & 7) << 4);
        f16x8 g = *(const f16x8*)((char*)gtile + byte);
        int n = nb + r;
        if (n < N) *(f16x8*)(gts + (size_t)n * GTOT + cb + c8 * 8) = g;
    }
}

// ---------- fused MFMA expert kernel: 32 rows/block, 4 waves, whole-h in LDS ----------
// Swapped both stages. A/B frag: 16-dim = lane&15, k = (lane>>4)*8+elem.
// C/D: col = lane&15 (B 16-dim), row = (lane>>4)*4+reg (A 16-dim)  [m89].
__global__ __launch_bounds__(256, 3) void moe_kernel(
    const float* __restrict__ x_emb, const float* __restrict__ wsm,
    const f16* __restrict__ gts,
    const f16* __restrict__ W1Th, const f16* __restrict__ W2Th,
    const float* __restrict__ ne_b1, const float* __restrict__ ne_b2,
    float* __restrict__ out, int N, int Mtot)
{
    __shared__ f16 xS[32 * 128];   // 8 KB, 256B pitch, swizzled
    __shared__ f16 hS[32 * 512];   // 32 KB, 1024B pitch, swizzled

    const int t = threadIdx.x;
    const int lane = t & 63, lr = lane & 15, lq = lane >> 4, wid = t >> 6;
    const int rowbase = blockIdx.x * 32;

    // stage x tile (f32 -> f16)
    for (int u = t; u < 32 * 32; u += 256) {
        int r = u >> 5, c4 = u & 31;
        int rg = rowbase + r; if (rg > Mtot - 1) rg = Mtot - 1;
        float4 v = *(const float4*)(x_emb + (size_t)rg * CD + c4 * 4);
        f16x4 hv; hv[0] = (f16)v.x; hv[1] = (f16)v.y; hv[2] = (f16)v.z; hv[3] = (f16)v.w;
        int byte = (r * 256 + c4 * 8) ^ ((r & 7) << 4);
        *(f16x4*)((char*)xS + byte) = hv;
    }

    // per-j row metadata (rows = j*16 + lr)
    int n_j[2], l_j[2];
    bool s0_j[2], val_j[2];
#pragma unroll
    for (int j = 0; j < 2; ++j) {
        int rl = j * 16 + lr;
        int rc = rowbase + rl; if (rc > Mtot - 1) rc = Mtot - 1;
        int n = rc / 25, s = rc - n * 25;
        n_j[j] = n;
        l_j[j] = (int)sqrtf((float)s);
        s0_j[j] = (s == 0);
        val_j[j] = (rowbase + rl) < Mtot;
    }

    f32x4 acco[2][2];
#pragma unroll
    for (int i = 0; i < 2; ++i) { acco[i][0] = (f32x4){0,0,0,0}; acco[i][1] = (f32x4){0,0,0,0}; }

    __syncthreads();

    for (int e = 0; e < 4; ++e) {
        const bool is_eq = (e < 2);
        const int goff = (e == 0) ? 0 : (e == 1) ? 2560 : (e == 2) ? 5120 : 5632;
        const f16* w1e = W1Th + ((size_t)e << 16);
        const f16* w2e = W2Th + ((size_t)e << 16);
        const f16* pg[2];
        float wk[2];
#pragma unroll
        for (int j = 0; j < 2; ++j) {
            pg[j] = gts + (size_t)n_j[j] * GTOT + goff + (is_eq ? l_j[j] * 512 : 0);
            wk[j] = wsm[(size_t)n_j[j] * 4 + e];
        }

        // ---- stage 1: h^T = W1T · x^T  (M=512 hcols split 4 waves, N=32 rows, K=128) ----
        f32x4 acc[8][2];
#pragma unroll
        for (int i = 0; i < 8; ++i) { acc[i][0] = (f32x4){0,0,0,0}; acc[i][1] = (f32x4){0,0,0,0}; }
#pragma unroll
        for (int ks = 0; ks < 4; ++ks) {
            f16x8 b[2], a[8];
#pragma unroll
            for (int j = 0; j < 2; ++j) {
                int rl = j * 16 + lr;
                int byte = (rl * 256 + (ks * 32 + lq * 8) * 2) ^ ((rl & 7) << 4);
                b[j] = *(const f16x8*)((char*)xS + byte);
            }
#pragma unroll
            for (int i = 0; i < 8; ++i)
                a[i] = *(const f16x8*)(w1e + (size_t)(wid * 128 + i * 16 + lr) * CD + ks * 32 + lq * 8);
#pragma unroll
            for (int i = 0; i < 8; ++i)
#pragma unroll
                for (int j = 0; j < 2; ++j)
                    acc[i][j] = __builtin_amdgcn_mfma_f32_16x16x32_f16(a[i], b[j], acc[i][j], 0, 0, 0);
        }
        __syncthreads();   // prev stage2 hS readers done

        // ---- epilogue: act + gate + wk, write hS ----
#pragma unroll
        for (int i = 0; i < 8; ++i) {
            const int hcolb = wid * 128 + i * 16 + lq * 4;
            float4 b1v = make_float4(0.f, 0.f, 0.f, 0.f);
            if (!is_eq) b1v = *(const float4*)(ne_b1 + (size_t)(e - 2) * HD + hcolb);
#pragma unroll
            for (int j = 0; j < 2; ++j) {
                float v0 = acc[i][j][0], v1 = acc[i][j][1], v2 = acc[i][j][2], v3 = acc[i][j][3];
                f16x4 g = *(const f16x4*)(pg[j] + hcolb);
                float w = wk[j];
                if (is_eq) {
                    if (s0_j[j]) { v0 = silu_f(v0); v1 = silu_f(v1); v2 = silu_f(v2); v3 = silu_f(v3); }
                } else {
                    v0 = silu_f(v0 + b1v.x); v1 = silu_f(v1 + b1v.y);
                    v2 = silu_f(v2 + b1v.z); v3 = silu_f(v3 + b1v.w);
                }
                f16x4 hv;
                hv[0] = (f16)(v0 * (float)g[0] * w);
                hv[1] = (f16)(v1 * (float)g[1] * w);
                hv[2] = (f16)(v2 * (float)g[2] * w);
                hv[3] = (f16)(v3 * (float)g[3] * w);
                int rl = j * 16 + lr;
                int byte = (rl * 1024 + hcolb * 2) ^ ((rl & 7) << 4);
                *(f16x4*)((char*)hS + byte) = hv;
            }
        }
        __syncthreads();   // hS visible

        // ---- stage 2: out^T += W2T · h^T  (M=128 c2 split 4 waves, N=32 rows, K=512) ----
#pragma unroll
        for (int ks = 0; ks < 16; ++ks) {
            f16x8 b2[2], a2[2];
#pragma unroll
            for (int j = 0; j < 2; ++j) {
                int rl = j * 16 + lr;
                int byte = (rl * 1024 + (ks * 32 + lq * 8) * 2) ^ ((rl & 7) << 4);
                b2[j] = *(const f16x8*)((char*)hS + byte);
            }
#pragma unroll
            for (int i = 0; i < 2; ++i)
                a2[i] = *(const f16x8*)(w2e + (size_t)(wid * 32 + i * 16 + lr) * HD + ks * 32 + lq * 8);
#pragma unroll
            for (int i = 0; i < 2; ++i)
#pragma unroll
                for (int j = 0; j < 2; ++j)
                    acco[i][j] = __builtin_amdgcn_mfma_f32_16x16x32_f16(a2[i], b2[j], acco[i][j], 0, 0, 0);
        }
    } // expert

    // ---- final epilogue ----
#pragma unroll
    for (int j = 0; j < 2; ++j) {
        if (!val_j[j]) continue;
        float wk2 = wsm[(size_t)n_j[j] * 4 + 2];
        float wk3 = wsm[(size_t)n_j[j] * 4 + 3];
#pragma unroll
        for (int i = 0; i < 2; ++i) {
            int c2b = wid * 32 + i * 16 + lq * 4;
            float4 ba = *(const float4*)(ne_b2 + c2b);
            float4 bb = *(const float4*)(ne_b2 + CD + c2b);
            float4 o;
            o.x = acco[i][j][0] + wk2 * ba.x + wk3 * bb.x;
            o.y = acco[i][j][1] + wk2 * ba.y + wk3 * bb.y;
            o.z = acco[i][j][2] + wk2 * ba.z + wk3 * bb.z;
            o.w = acco[i][j][3] + wk2 * ba.w + wk3 * bb.w;
            *(float4*)(out + (size_t)(rowbase + j * 16 + lr) * CD + c2b) = o;
        }
    }
}

extern "C" void kernel_launch(void* const* d_in, const int* in_sizes, int n_in,
                              void* d_out, int out_size, void* d_ws, size_t ws_size,
                              hipStream_t stream) {
    const float* x_emb = (const float*)d_in[0];
    const float* t_ij  = (const float*)d_in[1];
    const int*   eidx  = (const int*)d_in[2];
    const float* rW1   = (const float*)d_in[3];
    const float* rb1   = (const float*)d_in[4];
    const float* rW2   = (const float*)d_in[5];
    const float* rb2   = (const float*)d_in[6];
    const float* eq_W1 = (const float*)d_in[7];
    const float* eq_gW = (const float*)d_in[8];
    const float* eq_gb = (const float*)d_in[9];
    const float* eq_W2 = (const float*)d_in[10];
    const float* ne_W1 = (const float*)d_in[11];
    const float* ne_b1 = (const float*)d_in[12];
    const float* ne_gW = (const float*)d_in[13];
    const float* ne_gb = (const float*)d_in[14];
    const float* ne_W2 = (const float*)d_in[15];
    const float* ne_b2 = (const float*)d_in[16];
    float* out = (float*)d_out;

    const int N = in_sizes[0] / (NS * CD);
    const int E = in_sizes[1] / CD;
    const int Mtot = N * NS;

    char* ws = (char*)d_ws;
    size_t off = 0;
    auto alloc = [&](size_t bytes) {
        void* p = ws + off;
        off = (off + bytes + 255) & ~(size_t)255;
        return p;
    };
    float* csum = (float*)alloc((size_t)N * CD * 4);   // becomes c_i in place
    float* cnt  = (float*)alloc((size_t)N * 4);
    float* wsm  = (float*)alloc((size_t)N * 4 * 4);
    f16*   gts  = (f16*)alloc((size_t)N * GTOT * 2);
    f16*   W1Th = (f16*)alloc((size_t)4 * HD * CD * 2);
    f16*   W2Th = (f16*)alloc((size_t)4 * HD * CD * 2);
    f16*   gPW  = (f16*)alloc((size_t)GTOT * CD * 2);
    float* gPB  = (float*)alloc((size_t)GTOT * 4);

    hipMemsetAsync(csum, 0, (size_t)N * CD * 4, stream);
    hipMemsetAsync(cnt,  0, (size_t)N * 4, stream);

    // weight cvt/packing
    cvtw1_k<<<(4 * HD * CD + 255) / 256, 256, 0, stream>>>(eq_W1, ne_W1, W1Th);
    cvtw2_k<<<(4 * HD * CD + 255) / 256, 256, 0, stream>>>(eq_W2, ne_W2, W2Th);
    cvtgw_k<<<(GTOT * CD + 255) / 256, 256, 0, stream>>>(eq_gW, eq_gb, ne_gW, ne_gb, gPW, gPB);

    // segment sums
    long tot_e = (long)E * 32;
    edge_kernel<<<(int)((tot_e + 255) / 256), 256, 0, stream>>>(t_ij, eidx + E, csum, cnt, E);

    // c_i + router weights
    gating_kernel<<<N, CD, 0, stream>>>(csum, cnt, rW1, rb1, rW2, rb2, wsm, N);

    // MFMA gate GEMM (all 6144 cols)
    dim3 gg((N + 31) / 32, GTOT / 256);
    gatemm_k<<<gg, 256, 0, stream>>>(csum, gPW, gPB, gts, N);

    // fused MFMA experts
    moe_kernel<<<(Mtot + 31) / 32, 256, 0, stream>>>(
        x_emb, wsm, gts, W1Th, W2Th, ne_b1, ne_b2, out, N, Mtot);
}